// Round 1
// baseline (352.217 us; speedup 1.0000x reference)
//
#include <hip/hip_runtime.h>
#include <math.h>

#define BATCH 16
#define LEN 480000
#define NDIM 9
#define CHUNK 4096
#define NCHUNK 118   /* ceil(480000/4096); last chunk = 768 elements */
#define AMP 0.1f

__device__ __forceinline__ float hw_fract(float x) {
#if __has_builtin(__builtin_amdgcn_fractf)
  return __builtin_amdgcn_fractf(x);
#else
  return x - floorf(x);
#endif
}
// sin(2*pi*x) for x in [0,1) — v_sin_f32 takes revolutions
__device__ __forceinline__ float hw_sin1(float x) {
#if __has_builtin(__builtin_amdgcn_sinf)
  return __builtin_amdgcn_sinf(x);
#else
  return __sinf(x * 6.283185307179586f);
#endif
}

// ---------------- Kernel A: per-chunk f64 sums of f0 ----------------
__global__ __launch_bounds__(256) void sg_partial(const float* __restrict__ f0,
                                                  double* __restrict__ part) {
  const int c = blockIdx.x, b = blockIdx.y, t = threadIdx.x;
  const float4* f4 = (const float4*)(f0 + (size_t)b * LEN);
  const int b4 = c * (CHUNK / 4);
  double s = 0.0;
#pragma unroll
  for (int p = 0; p < 4; ++p) {
    int i4 = b4 + p * 256 + t;
    if (i4 < LEN / 4) {
      float4 v = f4[i4];
      s += (double)((v.x + v.y) + (v.z + v.w));
    }
  }
#pragma unroll
  for (int d = 32; d > 0; d >>= 1) s += __shfl_down(s, d, 64);
  __shared__ double ws[4];
  if ((t & 63) == 0) ws[t >> 6] = s;
  __syncthreads();
  if (t == 0) part[b * NCHUNK + c] = (ws[0] + ws[1]) + (ws[2] + ws[3]);
}

// ---------------- Kernel B: exclusive scan of chunk sums per batch ----------------
__global__ void sg_scan(const double* __restrict__ part, double* __restrict__ off) {
  const int b = threadIdx.x;
  if (b < BATCH) {
    double run = 0.0;
    for (int c = 0; c < NCHUNK; ++c) {
      off[b * NCHUNK + c] = run;
      run += part[b * NCHUNK + c];
    }
  }
}

// ---------------- Kernel C: main — scan within chunk, sin, coalesced stores ----------------
__global__ __launch_bounds__(256) void sg_main(const float* __restrict__ f0,
                                               const float* __restrict__ rand_ini,
                                               const double* __restrict__ off,
                                               float* __restrict__ out) {
  const int c = blockIdx.x, b = blockIdx.y, t = threadIdx.x;
  const int lane = t & 63, w = t >> 6;

  __shared__ float4 tile[2304];   // 1024 elements * 9 harmonics per pass = 36 KB
  __shared__ float wsc[4];

  const float4* f4 = (const float4*)(f0 + (size_t)b * LEN);
  const int base = c * CHUNK;
  const int valid = min(CHUNK, LEN - base);

  // load 16 elements/thread: pass p covers elements base + 1024p + 4t .. +3 (coalesced f4)
  float fv[4][4];
  float gs[4];
#pragma unroll
  for (int p = 0; p < 4; ++p) {
    int i4 = base / 4 + p * 256 + t;
    float4 v = make_float4(0.f, 0.f, 0.f, 0.f);
    if (i4 < LEN / 4) v = f4[i4];
    fv[p][0] = v.x; fv[p][1] = v.y; fv[p][2] = v.z; fv[p][3] = v.w;
    gs[p] = (v.x + v.y) + (v.z + v.w);
  }

  // 4 ordered block exclusive scans over group index g = 256p + t
  float goff[4];
  float running = 0.f;
#pragma unroll
  for (int p = 0; p < 4; ++p) {
    float x = gs[p];
#pragma unroll
    for (int d = 1; d < 64; d <<= 1) {
      float y = __shfl_up(x, d, 64);
      if (lane >= d) x += y;
    }
    if (lane == 63) wsc[w] = x;       // wave inclusive totals
    __syncthreads();
    float t0 = wsc[0], t1 = wsc[1], t2 = wsc[2], t3 = wsc[3];
    float tot  = (t0 + t1) + (t2 + t3);
    float wpre = (w > 0 ? t0 : 0.f) + (w > 1 ? t1 : 0.f) + (w > 2 ? t2 : 0.f);
    goff[p] = running + wpre + (x - gs[p]);   // exclusive prefix for this thread's group
    running += tot;
    __syncthreads();
  }

  // per-harmonic base phase: frac(rand + h/24000 * chunk_base) in f64 once
  const double cb = off[b * NCHUNK + c];
  float phi0[NDIM], hsf[NDIM];
#pragma unroll
  for (int h = 0; h < NDIM; ++h) {
    double hs = (double)(h + 1) * (1.0 / 24000.0);
    double p0 = (double)rand_ini[b * NDIM + h] + hs * cb;
    p0 -= floor(p0);
    phi0[h] = (float)p0;
    hsf[h] = (float)hs;
  }

  float4* out4 = (float4*)out;
  const size_t sine4_rowbase = ((size_t)b * LEN * NDIM) / 4;
  const size_t uv4_base = ((size_t)BATCH * LEN * NDIM) / 4 + ((size_t)b * LEN) / 4;

#pragma unroll
  for (int p = 0; p < 4; ++p) {
    const int ebase = base + p * 1024 + 4 * t;
    float P = goff[p];
    float sv[4][NDIM];
    float uvv[4];
#pragma unroll
    for (int e = 0; e < 4; ++e) {
      float f = fv[p][e];
      P += f;                       // inclusive prefix (relative to chunk)
      uvv[e] = (f > 0.f) ? 1.f : 0.f;
      float amp = AMP * uvv[e];
#pragma unroll
      for (int h = 0; h < NDIM; ++h) {
        float ph = hw_fract(phi0[h] + hsf[h] * P);
        sv[e][h] = amp * hw_sin1(ph);
      }
    }
    // stage 36 floats -> LDS as 9 float4 (f4 idx 9t+j; idx%8 distinct per 8 lanes)
#pragma unroll
    for (int j = 0; j < 9; ++j) {
      const int i0 = 4 * j;
      tile[t * 9 + j] = make_float4(sv[(i0    ) / 9][(i0    ) % 9],
                                    sv[(i0 + 1) / 9][(i0 + 1) % 9],
                                    sv[(i0 + 2) / 9][(i0 + 2) % 9],
                                    sv[(i0 + 3) / 9][(i0 + 3) % 9]);
    }
    // uv: directly lane-contiguous float4
    if (ebase < LEN)
      out4[uv4_base + (size_t)(base + p * 1024) / 4 + t] =
          make_float4(uvv[0], uvv[1], uvv[2], uvv[3]);
    __syncthreads();
    // coalesced copy LDS -> global
    const int pv = min(max(valid - p * 1024, 0), 1024);
    const int nf4 = (pv * NDIM) >> 2;
    const size_t gb4 = sine4_rowbase + (size_t)(base + p * 1024) * NDIM / 4;
#pragma unroll
    for (int k = 0; k < 9; ++k) {
      int idx = k * 256 + t;
      if (idx < nf4) out4[gb4 + idx] = tile[idx];
    }
    __syncthreads();
  }
}

extern "C" void kernel_launch(void* const* d_in, const int* in_sizes, int n_in,
                              void* d_out, int out_size, void* d_ws, size_t ws_size,
                              hipStream_t stream) {
  const float* f0 = (const float*)d_in[0];
  const float* rand_ini = (const float*)d_in[1];
  float* out = (float*)d_out;

  double* part = (double*)d_ws;                       // BATCH*NCHUNK f64
  double* off  = part + (size_t)BATCH * NCHUNK;       // BATCH*NCHUNK f64

  dim3 grid(NCHUNK, BATCH);
  sg_partial<<<grid, 256, 0, stream>>>(f0, part);
  sg_scan<<<1, 64, 0, stream>>>(part, off);
  sg_main<<<grid, 256, 0, stream>>>(f0, rand_ini, off, out);
}

// Round 2
// 331.623 us; speedup vs baseline: 1.0621x; 1.0621x over previous
//
#include <hip/hip_runtime.h>
#include <math.h>

#define BATCH 16
#define LEN 480000
#define NDIM 9
#define CHUNK 1024
#define NCHUNK 469   /* ceil(480000/1024); last chunk = 768 elements */
#define AMP 0.1f

__device__ __forceinline__ float hw_fract(float x) {
#if __has_builtin(__builtin_amdgcn_fractf)
  return __builtin_amdgcn_fractf(x);
#else
  return x - floorf(x);
#endif
}
// sin(2*pi*x) for x in [0,1) — v_sin_f32 takes revolutions
__device__ __forceinline__ float hw_sin1(float x) {
#if __has_builtin(__builtin_amdgcn_sinf)
  return __builtin_amdgcn_sinf(x);
#else
  return __sinf(x * 6.283185307179586f);
#endif
}

// ---------------- Kernel A: per-1024-chunk f64 sums of f0 ----------------
__global__ __launch_bounds__(256) void sg_partial(const float* __restrict__ f0,
                                                  double* __restrict__ part) {
  const int c = blockIdx.x, b = blockIdx.y, t = threadIdx.x;
  const int i4 = c * 256 + t;
  float4 v = make_float4(0.f, 0.f, 0.f, 0.f);
  if (i4 < LEN / 4) v = ((const float4*)(f0 + (size_t)b * LEN))[i4];
  double s = (double)((v.x + v.y) + (v.z + v.w));
#pragma unroll
  for (int d = 32; d > 0; d >>= 1) s += __shfl_down(s, d, 64);
  __shared__ double ws[4];
  if ((t & 63) == 0) ws[t >> 6] = s;
  __syncthreads();
  if (t == 0) part[(size_t)b * NCHUNK + c] = (ws[0] + ws[1]) + (ws[2] + ws[3]);
}

// ---------------- Kernel B: main — base-sum + scan + sin + coalesced stores ----------------
__global__ __launch_bounds__(256) void sg_main(const float* __restrict__ f0,
                                               const float* __restrict__ rand_ini,
                                               const double* __restrict__ part,
                                               float* __restrict__ out) {
  const int c = blockIdx.x, b = blockIdx.y, t = threadIdx.x;
  const int lane = t & 63, w = t >> 6;

  __shared__ float4 tile[2304];   // 1024 elements * 9 harmonics = 36 KB
  __shared__ float wsc[4];
  __shared__ double dred[4];
  __shared__ double cbs_s;

  // --- load this thread's 4 elements (coalesced float4) ---
  const int i4 = c * 256 + t;
  float4 v = make_float4(0.f, 0.f, 0.f, 0.f);
  if (i4 < LEN / 4) v = ((const float4*)(f0 + (size_t)b * LEN))[i4];
  const float fvv0 = v.x, fvv1 = v.y, fvv2 = v.z, fvv3 = v.w;
  const float gs = (v.x + v.y) + (v.z + v.w);

  // --- block-parallel f64 sum of preceding chunk sums: base = sum part[b][i], i<c ---
  const double* prow = part + (size_t)b * NCHUNK;
  double s = 0.0;
  if (t < c) s += prow[t];
  if (t + 256 < c) s += prow[t + 256];
#pragma unroll
  for (int d = 32; d > 0; d >>= 1) s += __shfl_down(s, d, 64);
  if (lane == 0) dred[w] = s;

  // --- wave-level inclusive scan of per-thread group sums ---
  float x = gs;
#pragma unroll
  for (int d = 1; d < 64; d <<= 1) {
    float y = __shfl_up(x, d, 64);
    if (lane >= d) x += y;
  }
  if (lane == 63) wsc[w] = x;
  __syncthreads();
  if (t == 0) cbs_s = (dred[0] + dred[1]) + (dred[2] + dred[3]);
  __syncthreads();

  const float t0 = wsc[0], t1 = wsc[1], t2 = wsc[2];
  const float wpre = (w > 0 ? t0 : 0.f) + (w > 1 ? t1 : 0.f) + (w > 2 ? t2 : 0.f);
  float P = wpre + (x - gs);            // exclusive in-chunk prefix for this thread

  // --- per-harmonic base phase: frac(rand + h/24000 * chunk_base), f64 once ---
  const double cb = cbs_s;
  float phi0[NDIM], hsf[NDIM];
#pragma unroll
  for (int h = 0; h < NDIM; ++h) {
    double hs = (double)(h + 1) * (1.0 / 24000.0);
    double p0 = (double)rand_ini[b * NDIM + h] + hs * cb;
    p0 -= floor(p0);
    phi0[h] = (float)p0;
    hsf[h] = (float)hs;
  }

  // --- sines for 4 elements x 9 harmonics ---
  float sv[4][NDIM];
  float uvv[4];
  const float fvv[4] = {fvv0, fvv1, fvv2, fvv3};
#pragma unroll
  for (int e = 0; e < 4; ++e) {
    const float f = fvv[e];
    P += f;                             // inclusive prefix (relative to chunk)
    uvv[e] = (f > 0.f) ? 1.f : 0.f;
    const float amp = AMP * uvv[e];
#pragma unroll
    for (int h = 0; h < NDIM; ++h)
      sv[e][h] = amp * hw_sin1(hw_fract(phi0[h] + hsf[h] * P));
  }

  // --- stage 36 floats -> LDS as 9 float4 (idx 9t+j: conflict-free in 8-lane phases) ---
#pragma unroll
  for (int j = 0; j < 9; ++j) {
    const int i0 = 4 * j;
    tile[t * 9 + j] = make_float4(sv[(i0    ) / 9][(i0    ) % 9],
                                  sv[(i0 + 1) / 9][(i0 + 1) % 9],
                                  sv[(i0 + 2) / 9][(i0 + 2) % 9],
                                  sv[(i0 + 3) / 9][(i0 + 3) % 9]);
  }
  __syncthreads();   // last barrier — no global stores issued yet

  // --- coalesced stores: sines then uv; nothing waits on them afterwards ---
  float4* out4 = (float4*)out;
  const int base = c * CHUNK;
  const int valid = min(CHUNK, LEN - base);
  const int nf4 = (valid * NDIM) >> 2;
  const size_t gb4 = ((size_t)b * LEN * NDIM + (size_t)base * NDIM) >> 2;
#pragma unroll
  for (int k = 0; k < 9; ++k) {
    const int idx = k * 256 + t;
    if (idx < nf4) out4[gb4 + idx] = tile[idx];
  }
  const size_t uv4_base = ((size_t)BATCH * LEN * NDIM) / 4 + ((size_t)b * LEN) / 4;
  if (i4 < LEN / 4)
    out4[uv4_base + i4] = make_float4(uvv[0], uvv[1], uvv[2], uvv[3]);
}

extern "C" void kernel_launch(void* const* d_in, const int* in_sizes, int n_in,
                              void* d_out, int out_size, void* d_ws, size_t ws_size,
                              hipStream_t stream) {
  const float* f0 = (const float*)d_in[0];
  const float* rand_ini = (const float*)d_in[1];
  float* out = (float*)d_out;

  double* part = (double*)d_ws;   // BATCH*NCHUNK f64 partial chunk sums

  dim3 grid(NCHUNK, BATCH);
  sg_partial<<<grid, 256, 0, stream>>>(f0, part);
  sg_main<<<grid, 256, 0, stream>>>(f0, rand_ini, part, out);
}